// Round 10
// baseline (171.709 us; speedup 1.0000x reference)
//
#include <hip/hip_runtime.h>
#include <hip/hip_bf16.h>
#include <hip/hip_cooperative_groups.h>

namespace cg = cooperative_groups;

// Problem constants
#define Bn   4
#define Cn   64
#define Hn   256
#define Wn   448
#define Gn   8                 // num_groups = C/8
#define CGn  8                 // channels per group
#define HWn  (Hn*Wn)           // 114688
#define CHWn (Cn*HWn)          // 7340032 (per batch)
#define NGn  (Bn*Gn)           // 32 (b,g) pairs
#define NBLKn 32               // row-chunks per (b,g) for stats partials
#define ROWS_PER_BLK (Hn/NBLKn)            // 8
#define ELEMS_PER_BLK (CGn*ROWS_PER_BLK*Wn) // 28672
#define VEC_PER_BLK  (ELEMS_PER_BLK/4)      // 7168 float4
#define VEC_PER_CHUNK ((ROWS_PER_BLK*Wn)/4) // 896 float4 per channel-chunk

typedef float f32x4 __attribute__((ext_vector_type(4)));

// ws layout (float offsets)
#define WS_PART 0                          // 1024*2 = 2048
#define WS_MEAN 2048                       // 32*2 = 64  (mean, rstd)
#define WS_FLAG 3000                       // 1 float: 1.0 => identity-gather certified
#define WS_RN   4096                       // (unused, kept for layout stability)
#define WS_SIM  (WS_RN + Bn*HWn)           // B*8*HW

// ---------------- fused cooperative: stats -> combine+cert -> apply ----------------
// 1024 blocks x 256 threads, 4 blocks/CU (16 waves/CU), grid-sync in middle.
// If certificate holds (flag=1): writes the final output (pure GN apply) and
// k_sim2/k_csamp no-op. If not: writes WS_MEAN/WS_FLAG and exits; the
// verified sim2+csamp fallback path runs unchanged.
__global__ __launch_bounds__(256, 4) void k_fused(const float* __restrict__ x,
                                                  const float* __restrict__ wgt,
                                                  const float* __restrict__ bias,
                                                  const float* __restrict__ ow,
                                                  const float* __restrict__ obias,
                                                  float* __restrict__ ws,
                                                  float* __restrict__ out) {
    const int tid = threadIdx.x;
    const int bid = blockIdx.x;          // 0..1023

    // ---- phase 1: per-(bg, rowchunk) partial sum/sumsq (same mapping as old k_stats1)
    {
        const int bg  = bid >> 5;        // 0..31
        const int blk = bid & 31;        // 0..31
        const int b = bg >> 3, g = bg & 7;
        const int r0 = blk * ROWS_PER_BLK;
        const float4* base = reinterpret_cast<const float4*>(
            x + (size_t)b*CHWn + (size_t)g*CGn*HWn + (size_t)r0*Wn);

        float s = 0.f, sq = 0.f;
        for (int i = tid; i < VEC_PER_BLK; i += 256) {
            int ci  = i / VEC_PER_CHUNK;
            int rem = i - ci*VEC_PER_CHUNK;
            float4 v = base[(size_t)ci*(HWn/4) + rem];
            s  += v.x + v.y + v.z + v.w;
            sq += v.x*v.x + v.y*v.y + v.z*v.z + v.w*v.w;
        }
        __shared__ float shs[4], shq[4];
        for (int o = 32; o > 0; o >>= 1) { s += __shfl_down(s, o); sq += __shfl_down(sq, o); }
        const int wid = tid >> 6;
        if ((tid & 63) == 0) { shs[wid] = s; shq[wid] = sq; }
        __syncthreads();
        if (tid == 0) {
            s  = shs[0] + shs[1] + shs[2] + shs[3];
            sq = shq[0] + shq[1] + shq[2] + shq[3];
            ws[WS_PART + (bid)*2 + 0] = s;
            ws[WS_PART + (bid)*2 + 1] = sq;
        }
    }

    cg::this_grid().sync();

    // ---- phase 2: combine partials (all 32 bg, per block) + certificate + affine
    __shared__ float mean_s[NGn], rstd_s[NGn];
    __shared__ float sc2[256], sh2[256];   // [b*64 + c]
    __shared__ float redA, redB, flag_s;

    {
        // combine: thread t -> bg = t>>3, i = t&7; each sums 4 partials
        const int bg2 = tid >> 3, i = tid & 7;
        float s = 0.f, sq = 0.f;
        #pragma unroll
        for (int k = 0; k < 4; ++k) {
            s  += ws[WS_PART + (bg2*32 + i*4 + k)*2 + 0];
            sq += ws[WS_PART + (bg2*32 + i*4 + k)*2 + 1];
        }
        for (int o = 4; o > 0; o >>= 1) { s += __shfl_down(s, o); sq += __shfl_down(sq, o); }
        if (i == 0) {
            const float n = (float)(CGn*HWn);
            float mean = s / n;
            float var  = sq / n - mean*mean;
            float rstd = 1.0f / sqrtf(var + 1e-5f);
            mean_s[bg2] = mean; rstd_s[bg2] = rstd;
            if (bid == 0) {
                ws[WS_MEAN + bg2*2 + 0] = mean;
                ws[WS_MEAN + bg2*2 + 1] = rstd;
            }
        }
        // certificate: wave 2 -> B0 over ow[0..71], wave 3 -> B1 over ow[72..143]
        if (tid >= 128 && tid < 192) {
            int l = tid - 128;
            float v = fabsf(ow[l]) + (l < 8 ? fabsf(ow[64 + l]) : 0.f);
            for (int o = 32; o > 0; o >>= 1) v += __shfl_down(v, o);
            if (l == 0) redA = v;
        }
        if (tid >= 192) {
            int l = tid - 192;
            float v = fabsf(ow[72 + l]) + (l < 8 ? fabsf(ow[136 + l]) : 0.f);
            for (int o = 32; o > 0; o >>= 1) v += __shfl_down(v, o);
            if (l == 0) redB = v;
        }
    }
    __syncthreads();
    if (tid == 0) {
        float B0 = fabsf(obias[0]) + redA;
        float B1 = fabsf(obias[1]) + redB;
        float f = (B0 < 0.499f && B1 < 0.499f) ? 1.0f : 0.0f;
        flag_s = f;
        if (bid == 0) ws[WS_FLAG] = f;
    }
    __syncthreads();

    if (flag_s == 0.0f) return;          // fallback: sim2 + csamp handle it

    // affine for all (b,c): thread t = b*64 + c
    {
        const int b2 = tid >> 6, c = tid & 63;
        float m = mean_s[b2*Gn + (c >> 3)], r = rstd_s[b2*Gn + (c >> 3)];
        float s = r * wgt[c];
        sc2[tid] = s;
        sh2[tid] = bias[c] - m * s;
    }
    __syncthreads();

    // ---- phase 3: certified apply — out = x*sc + sh, identity gather
    {
        const float4* x4 = reinterpret_cast<const float4*>(x);
        f32x4* o4 = reinterpret_cast<f32x4*>(out);
        const unsigned total4 = (unsigned)(Bn*(CHWn/4));     // 7340032
        const unsigned stride = 1024u*256u;                  // 262144
        for (unsigned idx = (unsigned)bid*256u + tid; idx < total4; idx += stride) {
            const unsigned bc = idx / (HWn/4);               // b*64+c, wave-uniform
            const float s = sc2[bc], t = sh2[bc];
            const float4 v = x4[idx];
            f32x4 ov;
            ov[0] = v.x*s + t; ov[1] = v.y*s + t;
            ov[2] = v.z*s + t; ov[3] = v.w*s + t;
            __builtin_nontemporal_store(ov, &o4[idx]);
        }
    }
}

// helper: load per-channel affine (scale, shift) into LDS. b uniform per block.
__device__ __forceinline__ void load_affine(const float* __restrict__ ws,
                                            const float* __restrict__ wgt,
                                            const float* __restrict__ bias,
                                            int b, float* sc, float* sh) {
    if (threadIdx.x < Cn) {
        int c = threadIdx.x;
        float mean = ws[WS_MEAN + (b*Gn + (c >> 3))*2 + 0];
        float rstd = ws[WS_MEAN + (b*Gn + (c >> 3))*2 + 1];
        float s = rstd * wgt[c];
        sc[c] = s;
        sh[c] = bias[c] - mean * s;
    }
    __syncthreads();
}

// ---------------- fallback: fused norm + cosine similarity, LDS-tiled ----------------
#define S_R4 18                 // float4 per staged row
#define S_ROWS 20
#define NSTG (S_ROWS*S_R4)      // 360 staged float4

#define STAGE_STEP(C, RA, RB, TB)                                              \
    {                                                                          \
        const float s_ = sc[(C)], t_ = sh[(C)];                                \
        float4 wv0, wv1;                                                       \
        wv0.x = val0 ? RA.x*s_ + t_ : 0.f;                                     \
        wv0.y = val0 ? RA.y*s_ + t_ : 0.f;                                     \
        wv0.z = val0 ? RA.z*s_ + t_ : 0.f;                                     \
        wv0.w = val0 ? RA.w*s_ + t_ : 0.f;                                     \
        wv1.x = val1 ? RB.x*s_ + t_ : 0.f;                                     \
        wv1.y = val1 ? RB.y*s_ + t_ : 0.f;                                     \
        wv1.z = val1 ? RB.z*s_ + t_ : 0.f;                                     \
        wv1.w = val1 ? RB.w*s_ + t_ : 0.f;                                     \
        TB[r0c*S_R4 + c40] = wv0;                                              \
        if (has1) TB[r1c*S_R4 + c41] = wv1;                                    \
        a0.x += wv0.x*wv0.x; a0.y += wv0.y*wv0.y;                              \
        a0.z += wv0.z*wv0.z; a0.w += wv0.w*wv0.w;                              \
        a1.x += wv1.x*wv1.x; a1.y += wv1.y*wv1.y;                              \
        a1.z += wv1.z*wv1.z; a1.w += wv1.w*wv1.w;                              \
        if ((C) + 2 < Cn) {                                                    \
            RA = xb[(size_t)((C)+2)*HW4 + off0];                               \
            RB = xb[(size_t)((C)+2)*HW4 + off1];                               \
        }                                                                      \
        __syncthreads();                                                       \
        const float4* tb = TB;                                                 \
        float4 m0 = tb[(prow  )*S_R4 + pc4], m1 = tb[(prow  )*S_R4 + pc4+1],   \
               m2 = tb[(prow  )*S_R4 + pc4+2];                                 \
        float4 z0 = tb[(prow+2)*S_R4 + pc4], z1 = tb[(prow+2)*S_R4 + pc4+1],   \
               z2 = tb[(prow+2)*S_R4 + pc4+2];                                 \
        float4 p0 = tb[(prow+4)*S_R4 + pc4], p1 = tb[(prow+4)*S_R4 + pc4+1],   \
               p2 = tb[(prow+4)*S_R4 + pc4+2];                                 \
        float vm[12] = {m0.x,m0.y,m0.z,m0.w, m1.x,m1.y,m1.z,m1.w,              \
                        m2.x,m2.y,m2.z,m2.w};                                  \
        float vz[12] = {z0.x,z0.y,z0.z,z0.w, z1.x,z1.y,z1.z,z1.w,              \
                        z2.x,z2.y,z2.z,z2.w};                                  \
        float vp[12] = {p0.x,p0.y,p0.z,p0.w, p1.x,p1.y,p1.z,p1.w,              \
                        p2.x,p2.y,p2.z,p2.w};                                  \
        _Pragma("unroll")                                                      \
        for (int j = 0; j < 4; ++j) {                                          \
            float xc = vz[4+j];                                                \
            dot[j][0] += xc*vm[2+j];                                           \
            dot[j][1] += xc*vm[4+j];                                           \
            dot[j][2] += xc*vm[6+j];                                           \
            dot[j][3] += xc*vz[2+j];                                           \
            dot[j][4] += xc*vz[6+j];                                           \
            dot[j][5] += xc*vp[2+j];                                           \
            dot[j][6] += xc*vp[4+j];                                           \
            dot[j][7] += xc*vp[6+j];                                           \
        }                                                                      \
    }

__global__ __launch_bounds__(256) void k_sim2(const float* __restrict__ x,
                                              const float* __restrict__ wgt,
                                              const float* __restrict__ bias,
                                              float* __restrict__ ws) {
    // identity-certified: sim is dead code, exit (uniform branch)
    if (ws[WS_FLAG] != 0.0f) return;

    __shared__ float sc[Cn], sh[Cn];
    __shared__ float4 tile[2][NSTG];
    __shared__ float4 n2s[NSTG];

    // XCD-chunked swizzle: 448 blocks, 56 consecutive (h-adjacent) per XCD
    int lin = blockIdx.x;
    int nid = (lin & 7) * 56 + (lin >> 3);
    int b   = nid / 112;
    int rem = nid - b*112;
    int th_ = rem / 7;
    int tw_ = rem - th_*7;
    const int h0 = th_*16, w0 = tw_*64;

    load_affine(ws, wgt, bias, b, sc, sh);

    const int tid = threadIdx.x;
    const int r0c = tid / S_R4, c40 = tid - r0c*S_R4;
    const int i1  = tid + 256;
    const bool has1 = (i1 < NSTG);
    const int r1c = i1 / S_R4, c41 = i1 - r1c*S_R4;

    const int gr0 = h0 - 2 + r0c, gc0 = (w0 >> 2) - 1 + c40;
    const bool val0 = (gr0 >= 0) & (gr0 < Hn) & (gc0 >= 0) & (gc0 < (Wn/4));
    const int gr1 = h0 - 2 + r1c, gc1 = (w0 >> 2) - 1 + c41;
    const bool val1 = has1 & (gr1 >= 0) & (gr1 < Hn) & (gc1 >= 0) & (gc1 < (Wn/4));

    const float4* xb = reinterpret_cast<const float4*>(x + (size_t)b*CHWn);
    const size_t HW4 = HWn/4;
    const size_t off0 = val0 ? ((size_t)gr0*(Wn/4) + gc0) : 0;
    const size_t off1 = val1 ? ((size_t)gr1*(Wn/4) + gc1) : 0;

    const int prow = tid >> 4;          // 0..15
    const int pc4  = tid & 15;          // 0..15

    float dot[4][8];
    #pragma unroll
    for (int j = 0; j < 4; ++j)
        #pragma unroll
        for (int k = 0; k < 8; ++k) dot[j][k] = 0.f;

    float4 a0 = {0,0,0,0}, a1 = {0,0,0,0};

    // depth-2 prefetch: channels 0 and 1 in flight before the loop
    float4 pa0 = xb[off0],        pb0 = xb[off1];
    float4 pa1 = xb[HW4 + off0],  pb1 = xb[HW4 + off1];

    for (int cc = 0; cc < Cn; cc += 2) {
        STAGE_STEP(cc,     pa0, pb0, tile[0]);
        STAGE_STEP(cc + 1, pa1, pb1, tile[1]);
    }

    n2s[r0c*S_R4 + c40] = a0;
    if (has1) n2s[r1c*S_R4 + c41] = a1;
    __syncthreads();

    {
        const float4* nb = n2s;
        float4 m0 = nb[(prow  )*S_R4 + pc4], m1 = nb[(prow  )*S_R4 + pc4+1], m2 = nb[(prow  )*S_R4 + pc4+2];
        float4 z0 = nb[(prow+2)*S_R4 + pc4], z1 = nb[(prow+2)*S_R4 + pc4+1], z2 = nb[(prow+2)*S_R4 + pc4+2];
        float4 p0 = nb[(prow+4)*S_R4 + pc4], p1 = nb[(prow+4)*S_R4 + pc4+1], p2 = nb[(prow+4)*S_R4 + pc4+2];
        float nm[12] = {m0.x,m0.y,m0.z,m0.w, m1.x,m1.y,m1.z,m1.w, m2.x,m2.y,m2.z,m2.w};
        float nz[12] = {z0.x,z0.y,z0.z,z0.w, z1.x,z1.y,z1.z,z1.w, z2.x,z2.y,z2.z,z2.w};
        float np_[12]= {p0.x,p0.y,p0.z,p0.w, p1.x,p1.y,p1.z,p1.w, p2.x,p2.y,p2.z,p2.w};
        float rm[8], rz[8], rp[8];
        #pragma unroll
        for (int e = 0; e < 8; ++e) {
            rm[e] = 1.0f / fmaxf(sqrtf(nm[2+e]), 1e-8f);
            rz[e] = 1.0f / fmaxf(sqrtf(nz[2+e]), 1e-8f);
            rp[e] = 1.0f / fmaxf(sqrtf(np_[2+e]), 1e-8f);
        }
        float* simb = ws + WS_SIM + (size_t)b*8*HWn + (size_t)(h0+prow)*Wn + (w0 + pc4*4);
        #pragma unroll
        for (int k = 0; k < 8; ++k) {
            f32x4 o;
            #pragma unroll
            for (int j = 0; j < 4; ++j) {
                float rnc = rz[2+j];
                float rnn;
                switch (k) {
                    case 0: rnn = rm[j];   break;
                    case 1: rnn = rm[2+j]; break;
                    case 2: rnn = rm[4+j]; break;
                    case 3: rnn = rz[j];   break;
                    case 4: rnn = rz[4+j]; break;
                    case 5: rnn = rp[j];   break;
                    case 6: rnn = rp[2+j]; break;
                    default: rnn = rp[4+j]; break;
                }
                o[j] = dot[j][k]*rnc*rnn;
            }
            *reinterpret_cast<f32x4*>(simb + (size_t)k*HWn) = o;
        }
    }
}

// ---------------- fallback: 3x3 convs + sigmoid gate + nearest-sample + out ----------------
__global__ __launch_bounds__(256) void k_csamp(const float* __restrict__ x,
                                               const float* __restrict__ wgt,
                                               const float* __restrict__ bias,
                                               const float* __restrict__ ow,
                                               const float* __restrict__ obias,
                                               const float* __restrict__ sw,
                                               const float* __restrict__ sbias,
                                               const float* __restrict__ ws,
                                               float* __restrict__ out) {
    // certified path: k_fused already wrote the output
    if (ws[WS_FLAG] != 0.0f) return;

    __shared__ float sc[Cn], sh[Cn];
    __shared__ float wo[144], wg[144];

    const int u  = blockIdx.x*256 + threadIdx.x;   // f4 index in [0, B*HW/4)
    const int b  = u / (HWn/4);
    const int r4 = u - b*(HWn/4);
    const int h  = r4 / (Wn/4);
    const int j  = r4 - h*(Wn/4);                  // f4 col 0..111

    load_affine(ws, wgt, bias, b, sc, sh);         // includes one __syncthreads
    for (int i = threadIdx.x; i < 144; i += 256) { wo[i] = ow[i]; wg[i] = sw[i]; }
    __syncthreads();

    float ao0[4], ao1[4], as0[4], as1[4];
    {
        const float b0 = obias[0], b1 = obias[1], c0 = sbias[0], c1 = sbias[1];
        #pragma unroll
        for (int p = 0; p < 4; ++p) { ao0[p] = b0; ao1[p] = b1; as0[p] = c0; as1[p] = c1; }
    }

    const float* simb = ws + WS_SIM + (size_t)b*8*HWn;
    #pragma unroll 2
    for (int kc = 0; kc < 8; ++kc) {
        const float* sp = simb + (size_t)kc*HWn;
        #pragma unroll
        for (int dy = -1; dy <= 1; ++dy) {
            const int hh = h + dy;
            const bool rowok = (hh >= 0) & (hh < Hn);
            const float* rowp = sp + (size_t)hh*Wn;
            float4 Bv = {0,0,0,0};
            float Aw = 0.f, Cx = 0.f;
            if (rowok) {
                Bv = reinterpret_cast<const float4*>(rowp)[j];
                if (j > 0)   Aw = rowp[4*j - 1];
                if (j < 111) Cx = rowp[4*j + 4];
            }
            float win[6] = {Aw, Bv.x, Bv.y, Bv.z, Bv.w, Cx};
            const int wi = kc*9 + (dy+1)*3;
            const float w00 = wo[wi], w01 = wo[wi+1], w02 = wo[wi+2];
            const float w10 = wo[wi+72], w11 = wo[wi+73], w12 = wo[wi+74];
            const float g00 = wg[wi], g01 = wg[wi+1], g02 = wg[wi+2];
            const float g10 = wg[wi+72], g11 = wg[wi+73], g12 = wg[wi+74];
            #pragma unroll
            for (int p = 0; p < 4; ++p) {
                const float t0 = win[p], t1 = win[p+1], t2 = win[p+2];
                ao0[p] += w00*t0 + w01*t1 + w02*t2;
                ao1[p] += w10*t0 + w11*t1 + w12*t2;
                as0[p] += g00*t0 + g01*t1 + g02*t2;
                as1[p] += g10*t0 + g11*t1 + g12*t2;
            }
        }
    }

    // offsets -> nearest indices (exact reference arithmetic, f32)
    int ixs[4], iys[4];
    #pragma unroll
    for (int p = 0; p < 4; ++p) {
        const float o0 = ao0[p] * (1.0f / (1.0f + expf(-as0[p])));
        const float o1 = ao1[p] * (1.0f / (1.0f + expf(-as1[p])));
        const int w = 4*j + p;
        float gx  = ((float)w + 0.5f) + o0;
        float gy  = ((float)h + 0.5f) + o1;
        float ngx = 2.0f*gx/(float)Wn - 1.0f;
        float ngy = 2.0f*gy/(float)Hn - 1.0f;
        float fx  = ((ngx + 1.0f)*(float)Wn - 1.0f)*0.5f;
        float fy  = ((ngy + 1.0f)*(float)Hn - 1.0f)*0.5f;
        ixs[p] = (int)fminf(fmaxf(rintf(fx), 0.f), (float)(Wn-1));
        iys[p] = (int)fminf(fmaxf(rintf(fy), 0.f), (float)(Hn-1));
    }

    const float* xb = x + (size_t)b*CHWn;
    float* po = out + (size_t)b*CHWn + (size_t)h*Wn + 4*j;

    // Fast path: all 4 gather indices equal this thread's own float4 cell
    const bool fast = (iys[0]==h) & (ixs[0]==4*j  ) &
                      (iys[1]==h) & (ixs[1]==4*j+1) &
                      (iys[2]==h) & (ixs[2]==4*j+2) &
                      (iys[3]==h) & (ixs[3]==4*j+3);
    if (fast) {
        const size_t o = (size_t)h*Wn + 4*j;
        #pragma unroll 8
        for (int c = 0; c < Cn; ++c) {
            const f32x4 v = *reinterpret_cast<const f32x4*>(xb + (size_t)c*HWn + o);
            const float s = sc[c], t = sh[c];
            f32x4 ov;
            ov[0] = v[0]*s + t; ov[1] = v[1]*s + t;
            ov[2] = v[2]*s + t; ov[3] = v[3]*s + t;
            __builtin_nontemporal_store(ov, reinterpret_cast<f32x4*>(po + (size_t)c*HWn));
        }
    } else {
        const int base0 = iys[0]*Wn + ixs[0];
        const int base1 = iys[1]*Wn + ixs[1];
        const int base2 = iys[2]*Wn + ixs[2];
        const int base3 = iys[3]*Wn + ixs[3];
        #pragma unroll 4
        for (int c = 0; c < Cn; ++c) {
            const float* pc = xb + (size_t)c*HWn;
            const float s = sc[c], t = sh[c];
            f32x4 o;
            o[0] = pc[base0]*s + t;
            o[1] = pc[base1]*s + t;
            o[2] = pc[base2]*s + t;
            o[3] = pc[base3]*s + t;
            __builtin_nontemporal_store(o, reinterpret_cast<f32x4*>(po + (size_t)c*HWn));
        }
    }
}

extern "C" void kernel_launch(void* const* d_in, const int* in_sizes, int n_in,
                              void* d_out, int out_size, void* d_ws, size_t ws_size,
                              hipStream_t stream) {
    const float* x     = (const float*)d_in[0];  // aligned_feat
    const float* wgt   = (const float*)d_in[3];  // gn_weight
    const float* bias  = (const float*)d_in[4];  // gn_bias
    const float* ow    = (const float*)d_in[5];  // offset_w (2,8,3,3)
    const float* ob    = (const float*)d_in[6];  // offset_b (2,)
    const float* sw    = (const float*)d_in[7];  // scale_w
    const float* sb    = (const float*)d_in[8];  // scale_b
    float* out = (float*)d_out;
    float* ws  = (float*)d_ws;

    void* args[] = {(void*)&x, (void*)&wgt, (void*)&bias, (void*)&ow,
                    (void*)&ob, (void*)&ws, (void*)&out};
    hipLaunchCooperativeKernel((void*)k_fused, dim3(1024), dim3(256), args, 0, stream);

    k_sim2 <<<448, 256, 0, stream>>>(x, wgt, bias, ws);
    k_csamp<<<(Bn*HWn/4)/256, 256, 0, stream>>>(x, wgt, bias, ow, ob, sw, sb, ws, out);
}

// Round 13
// 62.322 us; speedup vs baseline: 2.7552x; 2.7552x over previous
//
#include <hip/hip_runtime.h>
#include <hip/hip_bf16.h>

// Problem constants
#define Bn   4
#define Cn   64
#define Hn   256
#define Wn   448
#define Gn   8                 // num_groups = C/8
#define CGn  8                 // channels per group
#define HWn  (Hn*Wn)           // 114688
#define CHWn (Cn*HWn)          // 7340032 (per batch)
#define NGn  (Bn*Gn)           // 32 (b,g) pairs
#define NBLKn 32               // row-chunks per (b,g) for stats partials
#define ROWS_PER_BLK (Hn/NBLKn)            // 8
#define ELEMS_PER_BLK (CGn*ROWS_PER_BLK*Wn) // 28672
#define VEC_PER_BLK  (ELEMS_PER_BLK/4)      // 7168 float4
#define VEC_PER_CHUNK ((ROWS_PER_BLK*Wn)/4) // 896 float4 per channel-chunk

typedef float f32x4 __attribute__((ext_vector_type(4)));

// ws layout (float offsets)
#define WS_PART 0                          // 1024*2 = 2048
#define WS_RN   4096                       // (unused, kept for layout stability)
#define WS_SIM  (WS_RN + Bn*HWn)           // B*8*HW

// ---------------- stats pass 1: per-(b,g,rowchunk) partial sum/sumsq ----------------
__global__ __launch_bounds__(256) void k_stats1(const float* __restrict__ x,
                                                float* __restrict__ ws) {
    const int bg  = blockIdx.x;       // 0..31
    const int blk = blockIdx.y;       // 0..31
    const int b = bg >> 3, g = bg & 7;
    const int r0 = blk * ROWS_PER_BLK;
    const float4* base = reinterpret_cast<const float4*>(
        x + (size_t)b*CHWn + (size_t)g*CGn*HWn + (size_t)r0*Wn);

    float s = 0.f, sq = 0.f;
    for (int i = threadIdx.x; i < VEC_PER_BLK; i += 256) {
        int ci  = i / VEC_PER_CHUNK;            // channel within group (0..7)
        int rem = i - ci*VEC_PER_CHUNK;
        float4 v = base[(size_t)ci*(HWn/4) + rem];
        s  += v.x + v.y + v.z + v.w;
        sq += v.x*v.x + v.y*v.y + v.z*v.z + v.w*v.w;
    }
    __shared__ float shs[4], shq[4];
    for (int o = 32; o > 0; o >>= 1) { s += __shfl_down(s, o); sq += __shfl_down(sq, o); }
    const int wid = threadIdx.x >> 6;
    if ((threadIdx.x & 63) == 0) { shs[wid] = s; shq[wid] = sq; }
    __syncthreads();
    if (threadIdx.x == 0) {
        s  = shs[0] + shs[1] + shs[2] + shs[3];
        sq = shq[0] + shq[1] + shq[2] + shq[3];
        ws[WS_PART + (bg*NBLKn + blk)*2 + 0] = s;
        ws[WS_PART + (bg*NBLKn + blk)*2 + 1] = sq;
    }
}

// ---------------- shared helpers ----------------
__device__ __forceinline__ float wave_sum64(float v) {
    for (int o = 32; o > 0; o >>= 1) v += __shfl_down(v, o);
    return v;
}

// identity-gather certificate:
//   |off_k| <= (|ob_k| + sum|ow_k|) * max(sigmoid) * max|sim| <= |ob_k| + sum|ow_k|
//   (|sim|<=1 since cosine, sigmoid<1). If both bounds < 0.499, every gather
//   index round(w+off)==w bit-exactly. IDENTICAL instruction sequence in every
//   kernel (same inputs -> bitwise-identical result -> consistent decisions).
__device__ __forceinline__ bool cert_identity(const float* __restrict__ ow,
                                              const float* __restrict__ obias,
                                              float* __restrict__ lds2) {
    const int tid = threadIdx.x;
    if (tid < 64) {
        float v = fabsf(ow[tid]) + (tid < 8 ? fabsf(ow[64 + tid]) : 0.f);
        v = wave_sum64(v);
        if (tid == 0) lds2[0] = fabsf(obias[0]) + v;
    } else if (tid < 128) {
        const int l = tid - 64;
        float v = fabsf(ow[72 + l]) + (l < 8 ? fabsf(ow[136 + l]) : 0.f);
        v = wave_sum64(v);
        if (l == 0) lds2[1] = fabsf(obias[1]) + v;
    }
    __syncthreads();
    return (lds2[0] < 0.499f) && (lds2[1] < 0.499f);
}

// combine all 8 groups of batch b from WS_PART partials -> mean_s[8], rstd_s[8]
__device__ __forceinline__ void combine_stats_b(const float* __restrict__ ws, int b,
                                                float* mean_s, float* rstd_s) {
    const int t = threadIdx.x;
    const int g = t >> 5, k = t & 31;       // 8 groups x 32 partials
    float s  = ws[WS_PART + ((b*Gn + g)*NBLKn + k)*2 + 0];
    float sq = ws[WS_PART + ((b*Gn + g)*NBLKn + k)*2 + 1];
    for (int o = 16; o > 0; o >>= 1) { s += __shfl_down(s, o, 32); sq += __shfl_down(sq, o, 32); }
    if (k == 0) {
        const float n = (float)(CGn*HWn);
        float mean = s / n;
        float var  = sq / n - mean*mean;
        mean_s[g] = mean;
        rstd_s[g] = 1.0f / sqrtf(var + 1e-5f);
    }
    __syncthreads();
}

// ---------------- certified apply: out = x*sc + sh, plane-mapped stream ----------------
// 1024 blocks: bid = (b*64+c)*4 + chunk. sc/sh block-uniform scalars.
__global__ __launch_bounds__(256) void k_apply(const float* __restrict__ x,
                                               const float* __restrict__ wgt,
                                               const float* __restrict__ bias,
                                               const float* __restrict__ ow,
                                               const float* __restrict__ obias,
                                               const float* __restrict__ ws,
                                               float* __restrict__ out) {
    __shared__ float lds2[2];
    __shared__ float scsh[2];
    if (!cert_identity(ow, obias, lds2)) return;   // fallback path owns the output

    const int bid = blockIdx.x;
    const int bc = bid >> 2, chunk = bid & 3;
    const int b = bc >> 6, c = bc & 63, g = c >> 3;
    const int t = threadIdx.x;

    if (t < 32) {
        float s  = ws[WS_PART + ((b*Gn + g)*NBLKn + t)*2 + 0];
        float sq = ws[WS_PART + ((b*Gn + g)*NBLKn + t)*2 + 1];
        for (int o = 16; o > 0; o >>= 1) { s += __shfl_down(s, o, 32); sq += __shfl_down(sq, o, 32); }
        if (t == 0) {
            const float n = (float)(CGn*HWn);
            float mean = s / n;
            float var  = sq / n - mean*mean;
            float rstd = 1.0f / sqrtf(var + 1e-5f);
            float sc = rstd * wgt[c];
            scsh[0] = sc;
            scsh[1] = bias[c] - mean * sc;
        }
    }
    __syncthreads();
    const float s = scsh[0], sh = scsh[1];

    const size_t base = (size_t)bc*(HWn/4) + (size_t)chunk*(HWn/16);  // chunk = 7168 f4
    const float4* x4 = reinterpret_cast<const float4*>(x) + base;
    f32x4* o4 = reinterpret_cast<f32x4*>(out) + base;

    #pragma unroll
    for (int it = 0; it < 7; ++it) {
        const int i0 = it*1024 + t;
        const float4 v0 = x4[i0      ];
        const float4 v1 = x4[i0 + 256];
        const float4 v2 = x4[i0 + 512];
        const float4 v3 = x4[i0 + 768];
        f32x4 a, b_, c_, d_;
        a[0]=v0.x*s+sh; a[1]=v0.y*s+sh; a[2]=v0.z*s+sh; a[3]=v0.w*s+sh;
        b_[0]=v1.x*s+sh; b_[1]=v1.y*s+sh; b_[2]=v1.z*s+sh; b_[3]=v1.w*s+sh;
        c_[0]=v2.x*s+sh; c_[1]=v2.y*s+sh; c_[2]=v2.z*s+sh; c_[3]=v2.w*s+sh;
        d_[0]=v3.x*s+sh; d_[1]=v3.y*s+sh; d_[2]=v3.z*s+sh; d_[3]=v3.w*s+sh;
        __builtin_nontemporal_store(a,  &o4[i0      ]);
        __builtin_nontemporal_store(b_, &o4[i0 + 256]);
        __builtin_nontemporal_store(c_, &o4[i0 + 512]);
        __builtin_nontemporal_store(d_, &o4[i0 + 768]);
    }
}

// ---------------- fallback: fused norm + cosine similarity, LDS-tiled ----------------
#define S_R4 18                 // float4 per staged row
#define S_ROWS 20
#define NSTG (S_ROWS*S_R4)      // 360 staged float4

#define STAGE_STEP(C, RA, RB, TB)                                              \
    {                                                                          \
        const float s_ = sc[(C)], t_ = sh[(C)];                                \
        float4 wv0, wv1;                                                       \
        wv0.x = val0 ? RA.x*s_ + t_ : 0.f;                                     \
        wv0.y = val0 ? RA.y*s_ + t_ : 0.f;                                     \
        wv0.z = val0 ? RA.z*s_ + t_ : 0.f;                                     \
        wv0.w = val0 ? RA.w*s_ + t_ : 0.f;                                     \
        wv1.x = val1 ? RB.x*s_ + t_ : 0.f;                                     \
        wv1.y = val1 ? RB.y*s_ + t_ : 0.f;                                     \
        wv1.z = val1 ? RB.z*s_ + t_ : 0.f;                                     \
        wv1.w = val1 ? RB.w*s_ + t_ : 0.f;                                     \
        TB[r0c*S_R4 + c40] = wv0;                                              \
        if (has1) TB[r1c*S_R4 + c41] = wv1;                                    \
        a0.x += wv0.x*wv0.x; a0.y += wv0.y*wv0.y;                              \
        a0.z += wv0.z*wv0.z; a0.w += wv0.w*wv0.w;                              \
        a1.x += wv1.x*wv1.x; a1.y += wv1.y*wv1.y;                              \
        a1.z += wv1.z*wv1.z; a1.w += wv1.w*wv1.w;                              \
        if ((C) + 2 < Cn) {                                                    \
            RA = xb[(size_t)((C)+2)*HW4 + off0];                               \
            RB = xb[(size_t)((C)+2)*HW4 + off1];                               \
        }                                                                      \
        __syncthreads();                                                       \
        const float4* tb = TB;                                                 \
        float4 m0 = tb[(prow  )*S_R4 + pc4], m1 = tb[(prow  )*S_R4 + pc4+1],   \
               m2 = tb[(prow  )*S_R4 + pc4+2];                                 \
        float4 z0 = tb[(prow+2)*S_R4 + pc4], z1 = tb[(prow+2)*S_R4 + pc4+1],   \
               z2 = tb[(prow+2)*S_R4 + pc4+2];                                 \
        float4 p0 = tb[(prow+4)*S_R4 + pc4], p1 = tb[(prow+4)*S_R4 + pc4+1],   \
               p2 = tb[(prow+4)*S_R4 + pc4+2];                                 \
        float vm[12] = {m0.x,m0.y,m0.z,m0.w, m1.x,m1.y,m1.z,m1.w,              \
                        m2.x,m2.y,m2.z,m2.w};                                  \
        float vz[12] = {z0.x,z0.y,z0.z,z0.w, z1.x,z1.y,z1.z,z1.w,              \
                        z2.x,z2.y,z2.z,z2.w};                                  \
        float vp[12] = {p0.x,p0.y,p0.z,p0.w, p1.x,p1.y,p1.z,p1.w,              \
                        p2.x,p2.y,p2.z,p2.w};                                  \
        _Pragma("unroll")                                                      \
        for (int j = 0; j < 4; ++j) {                                          \
            float xc = vz[4+j];                                                \
            dot[j][0] += xc*vm[2+j];                                           \
            dot[j][1] += xc*vm[4+j];                                           \
            dot[j][2] += xc*vm[6+j];                                           \
            dot[j][3] += xc*vz[2+j];                                           \
            dot[j][4] += xc*vz[6+j];                                           \
            dot[j][5] += xc*vp[2+j];                                           \
            dot[j][6] += xc*vp[4+j];                                           \
            dot[j][7] += xc*vp[6+j];                                           \
        }                                                                      \
    }

__global__ __launch_bounds__(256) void k_sim2(const float* __restrict__ x,
                                              const float* __restrict__ wgt,
                                              const float* __restrict__ bias,
                                              const float* __restrict__ ow,
                                              const float* __restrict__ obias,
                                              float* __restrict__ ws) {
    __shared__ float lds2[2];
    __shared__ float mean_s[Gn], rstd_s[Gn];
    __shared__ float sc[Cn], sh[Cn];
    __shared__ float4 tile[2][NSTG];
    __shared__ float4 n2s[NSTG];

    if (cert_identity(ow, obias, lds2)) return;   // certified: sim is dead code

    // XCD-chunked swizzle: 448 blocks, 56 consecutive (h-adjacent) per XCD
    int lin = blockIdx.x;
    int nid = (lin & 7) * 56 + (lin >> 3);
    int b   = nid / 112;
    int rem = nid - b*112;
    int th_ = rem / 7;
    int tw_ = rem - th_*7;
    const int h0 = th_*16, w0 = tw_*64;

    combine_stats_b(ws, b, mean_s, rstd_s);
    if (threadIdx.x < Cn) {
        int c = threadIdx.x;
        float s = rstd_s[c >> 3] * wgt[c];
        sc[c] = s;
        sh[c] = bias[c] - mean_s[c >> 3] * s;
    }
    __syncthreads();

    const int tid = threadIdx.x;
    const int r0c = tid / S_R4, c40 = tid - r0c*S_R4;
    const int i1  = tid + 256;
    const bool has1 = (i1 < NSTG);
    const int r1c = i1 / S_R4, c41 = i1 - r1c*S_R4;

    const int gr0 = h0 - 2 + r0c, gc0 = (w0 >> 2) - 1 + c40;
    const bool val0 = (gr0 >= 0) & (gr0 < Hn) & (gc0 >= 0) & (gc0 < (Wn/4));
    const int gr1 = h0 - 2 + r1c, gc1 = (w0 >> 2) - 1 + c41;
    const bool val1 = has1 & (gr1 >= 0) & (gr1 < Hn) & (gc1 >= 0) & (gc1 < (Wn/4));

    const float4* xb = reinterpret_cast<const float4*>(x + (size_t)b*CHWn);
    const size_t HW4 = HWn/4;
    const size_t off0 = val0 ? ((size_t)gr0*(Wn/4) + gc0) : 0;
    const size_t off1 = val1 ? ((size_t)gr1*(Wn/4) + gc1) : 0;

    const int prow = tid >> 4;          // 0..15
    const int pc4  = tid & 15;          // 0..15

    float dot[4][8];
    #pragma unroll
    for (int j = 0; j < 4; ++j)
        #pragma unroll
        for (int k = 0; k < 8; ++k) dot[j][k] = 0.f;

    float4 a0 = {0,0,0,0}, a1 = {0,0,0,0};

    // depth-2 prefetch: channels 0 and 1 in flight before the loop
    float4 pa0 = xb[off0],        pb0 = xb[off1];
    float4 pa1 = xb[HW4 + off0],  pb1 = xb[HW4 + off1];

    for (int cc = 0; cc < Cn; cc += 2) {
        STAGE_STEP(cc,     pa0, pb0, tile[0]);
        STAGE_STEP(cc + 1, pa1, pb1, tile[1]);
    }

    n2s[r0c*S_R4 + c40] = a0;
    if (has1) n2s[r1c*S_R4 + c41] = a1;
    __syncthreads();

    {
        const float4* nb = n2s;
        float4 m0 = nb[(prow  )*S_R4 + pc4], m1 = nb[(prow  )*S_R4 + pc4+1], m2 = nb[(prow  )*S_R4 + pc4+2];
        float4 z0 = nb[(prow+2)*S_R4 + pc4], z1 = nb[(prow+2)*S_R4 + pc4+1], z2 = nb[(prow+2)*S_R4 + pc4+2];
        float4 p0 = nb[(prow+4)*S_R4 + pc4], p1 = nb[(prow+4)*S_R4 + pc4+1], p2 = nb[(prow+4)*S_R4 + pc4+2];
        float nm[12] = {m0.x,m0.y,m0.z,m0.w, m1.x,m1.y,m1.z,m1.w, m2.x,m2.y,m2.z,m2.w};
        float nz[12] = {z0.x,z0.y,z0.z,z0.w, z1.x,z1.y,z1.z,z1.w, z2.x,z2.y,z2.z,z2.w};
        float np_[12]= {p0.x,p0.y,p0.z,p0.w, p1.x,p1.y,p1.z,p1.w, p2.x,p2.y,p2.z,p2.w};
        float rm[8], rz[8], rp[8];
        #pragma unroll
        for (int e = 0; e < 8; ++e) {
            rm[e] = 1.0f / fmaxf(sqrtf(nm[2+e]), 1e-8f);
            rz[e] = 1.0f / fmaxf(sqrtf(nz[2+e]), 1e-8f);
            rp[e] = 1.0f / fmaxf(sqrtf(np_[2+e]), 1e-8f);
        }
        float* simb = ws + WS_SIM + (size_t)b*8*HWn + (size_t)(h0+prow)*Wn + (w0 + pc4*4);
        #pragma unroll
        for (int k = 0; k < 8; ++k) {
            f32x4 o;
            #pragma unroll
            for (int j = 0; j < 4; ++j) {
                float rnc = rz[2+j];
                float rnn;
                switch (k) {
                    case 0: rnn = rm[j];   break;
                    case 1: rnn = rm[2+j]; break;
                    case 2: rnn = rm[4+j]; break;
                    case 3: rnn = rz[j];   break;
                    case 4: rnn = rz[4+j]; break;
                    case 5: rnn = rp[j];   break;
                    case 6: rnn = rp[2+j]; break;
                    default: rnn = rp[4+j]; break;
                }
                o[j] = dot[j][k]*rnc*rnn;
            }
            *reinterpret_cast<f32x4*>(simb + (size_t)k*HWn) = o;
        }
    }
}

// ---------------- fallback: 3x3 convs + sigmoid gate + nearest-sample + out ----------------
__global__ __launch_bounds__(256) void k_csamp(const float* __restrict__ x,
                                               const float* __restrict__ wgt,
                                               const float* __restrict__ bias,
                                               const float* __restrict__ ow,
                                               const float* __restrict__ obias,
                                               const float* __restrict__ sw,
                                               const float* __restrict__ sbias,
                                               const float* __restrict__ ws,
                                               float* __restrict__ out) {
    __shared__ float lds2[2];
    __shared__ float mean_s[Gn], rstd_s[Gn];
    __shared__ float sc[Cn], sh[Cn];
    __shared__ float wo[144], wg[144];

    if (cert_identity(ow, obias, lds2)) return;   // certified: k_apply wrote out

    const int u  = blockIdx.x*256 + threadIdx.x;   // f4 index in [0, B*HW/4)
    const int b  = u / (HWn/4);
    const int r4 = u - b*(HWn/4);
    const int h  = r4 / (Wn/4);
    const int j  = r4 - h*(Wn/4);                  // f4 col 0..111

    combine_stats_b(ws, b, mean_s, rstd_s);        // b uniform per block
    if (threadIdx.x < Cn) {
        int c = threadIdx.x;
        float s = rstd_s[c >> 3] * wgt[c];
        sc[c] = s;
        sh[c] = bias[c] - mean_s[c >> 3] * s;
    }
    for (int i = threadIdx.x; i < 144; i += 256) { wo[i] = ow[i]; wg[i] = sw[i]; }
    __syncthreads();

    float ao0[4], ao1[4], as0[4], as1[4];
    {
        const float b0 = obias[0], b1 = obias[1], c0 = sbias[0], c1 = sbias[1];
        #pragma unroll
        for (int p = 0; p < 4; ++p) { ao0[p] = b0; ao1[p] = b1; as0[p] = c0; as1[p] = c1; }
    }

    const float* simb = ws + WS_SIM + (size_t)b*8*HWn;
    #pragma unroll 2
    for (int kc = 0; kc < 8; ++kc) {
        const float* sp = simb + (size_t)kc*HWn;
        #pragma unroll
        for (int dy = -1; dy <= 1; ++dy) {
            const int hh = h + dy;
            const bool rowok = (hh >= 0) & (hh < Hn);
            const float* rowp = sp + (size_t)hh*Wn;
            float4 Bv = {0,0,0,0};
            float Aw = 0.f, Cx = 0.f;
            if (rowok) {
                Bv = reinterpret_cast<const float4*>(rowp)[j];
                if (j > 0)   Aw = rowp[4*j - 1];
                if (j < 111) Cx = rowp[4*j + 4];
            }
            float win[6] = {Aw, Bv.x, Bv.y, Bv.z, Bv.w, Cx};
            const int wi = kc*9 + (dy+1)*3;
            const float w00 = wo[wi], w01 = wo[wi+1], w02 = wo[wi+2];
            const float w10 = wo[wi+72], w11 = wo[wi+73], w12 = wo[wi+74];
            const float g00 = wg[wi], g01 = wg[wi+1], g02 = wg[wi+2];
            const float g10 = wg[wi+72], g11 = wg[wi+73], g12 = wg[wi+74];
            #pragma unroll
            for (int p = 0; p < 4; ++p) {
                const float t0 = win[p], t1 = win[p+1], t2 = win[p+2];
                ao0[p] += w00*t0 + w01*t1 + w02*t2;
                ao1[p] += w10*t0 + w11*t1 + w12*t2;
                as0[p] += g00*t0 + g01*t1 + g02*t2;
                as1[p] += g10*t0 + g11*t1 + g12*t2;
            }
        }
    }

    // offsets -> nearest indices (exact reference arithmetic, f32)
    int ixs[4], iys[4];
    #pragma unroll
    for (int p = 0; p < 4; ++p) {
        const float o0 = ao0[p] * (1.0f / (1.0f + expf(-as0[p])));
        const float o1 = ao1[p] * (1.0f / (1.0f + expf(-as1[p])));
        const int w = 4*j + p;
        float gx  = ((float)w + 0.5f) + o0;
        float gy  = ((float)h + 0.5f) + o1;
        float ngx = 2.0f*gx/(float)Wn - 1.0f;
        float ngy = 2.0f*gy/(float)Hn - 1.0f;
        float fx  = ((ngx + 1.0f)*(float)Wn - 1.0f)*0.5f;
        float fy  = ((ngy + 1.0f)*(float)Hn - 1.0f)*0.5f;
        ixs[p] = (int)fminf(fmaxf(rintf(fx), 0.f), (float)(Wn-1));
        iys[p] = (int)fminf(fmaxf(rintf(fy), 0.f), (float)(Hn-1));
    }

    const float* xb = x + (size_t)b*CHWn;
    float* po = out + (size_t)b*CHWn + (size_t)h*Wn + 4*j;

    // Fast path: all 4 gather indices equal this thread's own float4 cell
    const bool fast = (iys[0]==h) & (ixs[0]==4*j  ) &
                      (iys[1]==h) & (ixs[1]==4*j+1) &
                      (iys[2]==h) & (ixs[2]==4*j+2) &
                      (iys[3]==h) & (ixs[3]==4*j+3);
    if (fast) {
        const size_t o = (size_t)h*Wn + 4*j;
        #pragma unroll 8
        for (int c = 0; c < Cn; ++c) {
            const f32x4 v = *reinterpret_cast<const f32x4*>(xb + (size_t)c*HWn + o);
            const float s = sc[c], t = sh[c];
            f32x4 ov;
            ov[0] = v[0]*s + t; ov[1] = v[1]*s + t;
            ov[2] = v[2]*s + t; ov[3] = v[3]*s + t;
            __builtin_nontemporal_store(ov, reinterpret_cast<f32x4*>(po + (size_t)c*HWn));
        }
    } else {
        const int base0 = iys[0]*Wn + ixs[0];
        const int base1 = iys[1]*Wn + ixs[1];
        const int base2 = iys[2]*Wn + ixs[2];
        const int base3 = iys[3]*Wn + ixs[3];
        #pragma unroll 4
        for (int c = 0; c < Cn; ++c) {
            const float* pc = xb + (size_t)c*HWn;
            const float s = sc[c], t = sh[c];
            f32x4 o;
            o[0] = pc[base0]*s + t;
            o[1] = pc[base1]*s + t;
            o[2] = pc[base2]*s + t;
            o[3] = pc[base3]*s + t;
            __builtin_nontemporal_store(o, reinterpret_cast<f32x4*>(po + (size_t)c*HWn));
        }
    }
}

extern "C" void kernel_launch(void* const* d_in, const int* in_sizes, int n_in,
                              void* d_out, int out_size, void* d_ws, size_t ws_size,
                              hipStream_t stream) {
    const float* x     = (const float*)d_in[0];  // aligned_feat
    const float* wgt   = (const float*)d_in[3];  // gn_weight
    const float* bias  = (const float*)d_in[4];  // gn_bias
    const float* ow    = (const float*)d_in[5];  // offset_w (2,8,3,3)
    const float* ob    = (const float*)d_in[6];  // offset_b (2,)
    const float* sw    = (const float*)d_in[7];  // scale_w
    const float* sb    = (const float*)d_in[8];  // scale_b
    float* out = (float*)d_out;
    float* ws  = (float*)d_ws;

    k_stats1<<<dim3(NGn, NBLKn), 256, 0, stream>>>(x, ws);
    k_sim2  <<<448, 256, 0, stream>>>(x, wgt, bias, ow, ob, ws);
    k_apply <<<1024, 256, 0, stream>>>(x, wgt, bias, ow, ob, ws, out);
    k_csamp <<<448, 256, 0, stream>>>(x, wgt, bias, ow, ob, sw, sb, ws, out);
}

// Round 14
// 61.646 us; speedup vs baseline: 2.7854x; 1.0110x over previous
//
#include <hip/hip_runtime.h>
#include <hip/hip_bf16.h>

// Problem constants
#define Bn   4
#define Cn   64
#define Hn   256
#define Wn   448
#define Gn   8                 // num_groups = C/8
#define CGn  8                 // channels per group
#define HWn  (Hn*Wn)           // 114688
#define CHWn (Cn*HWn)          // 7340032 (per batch)
#define NGn  (Bn*Gn)           // 32 (b,g) pairs
#define NBLKn 32               // row-chunks per (b,g) for stats partials
#define ROWS_PER_BLK (Hn/NBLKn)            // 8
#define ELEMS_PER_BLK (CGn*ROWS_PER_BLK*Wn) // 28672
#define VEC_PER_BLK  (ELEMS_PER_BLK/4)      // 7168 float4
#define VEC_PER_CHUNK ((ROWS_PER_BLK*Wn)/4) // 896 float4 per channel-chunk

typedef float f32x4 __attribute__((ext_vector_type(4)));

// ws layout (float offsets)
#define WS_PART 0                          // 1024*2 = 2048
#define WS_FLAG 3000                       // 1 float: 1.0 => identity-gather certified
#define WS_RN   4096                       // (unused, kept for layout stability)
#define WS_SIM  (WS_RN + Bn*HWn)           // B*8*HW

// ---------------- stats pass 1: per-(b,g,rowchunk) partial sum/sumsq ----------------
__global__ __launch_bounds__(256) void k_stats1(const float* __restrict__ x,
                                                float* __restrict__ ws) {
    const int bg  = blockIdx.x;       // 0..31
    const int blk = blockIdx.y;       // 0..31
    const int b = bg >> 3, g = bg & 7;
    const int r0 = blk * ROWS_PER_BLK;
    const float4* base = reinterpret_cast<const float4*>(
        x + (size_t)b*CHWn + (size_t)g*CGn*HWn + (size_t)r0*Wn);

    float s = 0.f, sq = 0.f;
    for (int i = threadIdx.x; i < VEC_PER_BLK; i += 256) {
        int ci  = i / VEC_PER_CHUNK;            // channel within group (0..7)
        int rem = i - ci*VEC_PER_CHUNK;
        float4 v = base[(size_t)ci*(HWn/4) + rem];
        s  += v.x + v.y + v.z + v.w;
        sq += v.x*v.x + v.y*v.y + v.z*v.z + v.w*v.w;
    }
    __shared__ float shs[4], shq[4];
    for (int o = 32; o > 0; o >>= 1) { s += __shfl_down(s, o); sq += __shfl_down(sq, o); }
    const int wid = threadIdx.x >> 6;
    if ((threadIdx.x & 63) == 0) { shs[wid] = s; shq[wid] = sq; }
    __syncthreads();
    if (threadIdx.x == 0) {
        s  = shs[0] + shs[1] + shs[2] + shs[3];
        sq = shq[0] + shq[1] + shq[2] + shq[3];
        ws[WS_PART + (bg*NBLKn + blk)*2 + 0] = s;
        ws[WS_PART + (bg*NBLKn + blk)*2 + 1] = sq;
    }
}

// ---------------- shared helpers ----------------
__device__ __forceinline__ float wave_sum64(float v) {
    for (int o = 32; o > 0; o >>= 1) v += __shfl_down(v, o);
    return v;
}

// identity-gather certificate (computed ONCE, in k_apply; published to WS_FLAG):
//   |off_k| <= (|ob_k| + sum|ow_k|) * max(sigmoid) * max|sim| <= |ob_k| + sum|ow_k|
//   (|sim|<=1 since cosine, sigmoid<1). If both bounds < 0.499, every gather
//   index round(w+off)==w bit-exactly -> sim/conv pipeline is dead code.
__device__ __forceinline__ bool cert_identity(const float* __restrict__ ow,
                                              const float* __restrict__ obias,
                                              float* __restrict__ lds2) {
    const int tid = threadIdx.x;
    if (tid < 64) {
        float v = fabsf(ow[tid]) + (tid < 8 ? fabsf(ow[64 + tid]) : 0.f);
        v = wave_sum64(v);
        if (tid == 0) lds2[0] = fabsf(obias[0]) + v;
    } else if (tid < 128) {
        const int l = tid - 64;
        float v = fabsf(ow[72 + l]) + (l < 8 ? fabsf(ow[136 + l]) : 0.f);
        v = wave_sum64(v);
        if (l == 0) lds2[1] = fabsf(obias[1]) + v;
    }
    __syncthreads();
    return (lds2[0] < 0.499f) && (lds2[1] < 0.499f);
}

// combine all 8 groups of batch b from WS_PART partials -> mean_s[8], rstd_s[8]
__device__ __forceinline__ void combine_stats_b(const float* __restrict__ ws, int b,
                                                float* mean_s, float* rstd_s) {
    const int t = threadIdx.x;
    const int g = t >> 5, k = t & 31;       // 8 groups x 32 partials
    float s  = ws[WS_PART + ((b*Gn + g)*NBLKn + k)*2 + 0];
    float sq = ws[WS_PART + ((b*Gn + g)*NBLKn + k)*2 + 1];
    for (int o = 16; o > 0; o >>= 1) { s += __shfl_down(s, o, 32); sq += __shfl_down(sq, o, 32); }
    if (k == 0) {
        const float n = (float)(CGn*HWn);
        float mean = s / n;
        float var  = sq / n - mean*mean;
        mean_s[g] = mean;
        rstd_s[g] = 1.0f / sqrtf(var + 1e-5f);
    }
    __syncthreads();
}

// ---------------- certified apply: out = x*sc + sh, plane-mapped stream ----------------
// 2048 blocks (8/CU): bid = (b*64+c)*8 + chunk; sc/sh block-uniform scalars.
// Runs immediately after k_stats1 so x is L3-resident. Publishes WS_FLAG.
__global__ __launch_bounds__(256) void k_apply(const float* __restrict__ x,
                                               const float* __restrict__ wgt,
                                               const float* __restrict__ bias,
                                               const float* __restrict__ ow,
                                               const float* __restrict__ obias,
                                               float* __restrict__ ws,
                                               float* __restrict__ out) {
    __shared__ float lds2[2];
    __shared__ float scsh[2];
    const bool ok = cert_identity(ow, obias, lds2);
    if (blockIdx.x == 0 && threadIdx.x == 0) ws[WS_FLAG] = ok ? 1.0f : 0.0f;
    if (!ok) return;                         // fallback path owns the output

    const int bid = blockIdx.x;
    const int bc = bid >> 3, chunk = bid & 7;
    const int b = bc >> 6, c = bc & 63, g = c >> 3;
    const int t = threadIdx.x;

    if (t < 32) {
        float s  = ws[WS_PART + ((b*Gn + g)*NBLKn + t)*2 + 0];
        float sq = ws[WS_PART + ((b*Gn + g)*NBLKn + t)*2 + 1];
        for (int o = 16; o > 0; o >>= 1) { s += __shfl_down(s, o, 32); sq += __shfl_down(sq, o, 32); }
        if (t == 0) {
            const float n = (float)(CGn*HWn);
            float mean = s / n;
            float var  = sq / n - mean*mean;
            float rstd = 1.0f / sqrtf(var + 1e-5f);
            float sc = rstd * wgt[c];
            scsh[0] = sc;
            scsh[1] = bias[c] - mean * sc;
        }
    }
    __syncthreads();
    const float s = scsh[0], sh = scsh[1];

    // chunk = HWn/32 f4 = 3584 f4 = 14 per thread
    const size_t base = (size_t)bc*(HWn/4) + (size_t)chunk*(HWn/32);
    const float4* x4 = reinterpret_cast<const float4*>(x) + base;
    f32x4* o4 = reinterpret_cast<f32x4*>(out) + base;

    #pragma unroll
    for (int it = 0; it < 14; ++it) {
        const int i = it*256 + t;
        const float4 v = x4[i];
        f32x4 ov;
        ov[0] = v.x*s + sh; ov[1] = v.y*s + sh;
        ov[2] = v.z*s + sh; ov[3] = v.w*s + sh;
        __builtin_nontemporal_store(ov, &o4[i]);
    }
}

// ---------------- fallback: fused norm + cosine similarity, LDS-tiled ----------------
#define S_R4 18                 // float4 per staged row
#define S_ROWS 20
#define NSTG (S_ROWS*S_R4)      // 360 staged float4

#define STAGE_STEP(C, RA, RB, TB)                                              \
    {                                                                          \
        const float s_ = sc[(C)], t_ = sh[(C)];                                \
        float4 wv0, wv1;                                                       \
        wv0.x = val0 ? RA.x*s_ + t_ : 0.f;                                     \
        wv0.y = val0 ? RA.y*s_ + t_ : 0.f;                                     \
        wv0.z = val0 ? RA.z*s_ + t_ : 0.f;                                     \
        wv0.w = val0 ? RA.w*s_ + t_ : 0.f;                                     \
        wv1.x = val1 ? RB.x*s_ + t_ : 0.f;                                     \
        wv1.y = val1 ? RB.y*s_ + t_ : 0.f;                                     \
        wv1.z = val1 ? RB.z*s_ + t_ : 0.f;                                     \
        wv1.w = val1 ? RB.w*s_ + t_ : 0.f;                                     \
        TB[r0c*S_R4 + c40] = wv0;                                              \
        if (has1) TB[r1c*S_R4 + c41] = wv1;                                    \
        a0.x += wv0.x*wv0.x; a0.y += wv0.y*wv0.y;                              \
        a0.z += wv0.z*wv0.z; a0.w += wv0.w*wv0.w;                              \
        a1.x += wv1.x*wv1.x; a1.y += wv1.y*wv1.y;                              \
        a1.z += wv1.z*wv1.z; a1.w += wv1.w*wv1.w;                              \
        if ((C) + 2 < Cn) {                                                    \
            RA = xb[(size_t)((C)+2)*HW4 + off0];                               \
            RB = xb[(size_t)((C)+2)*HW4 + off1];                               \
        }                                                                      \
        __syncthreads();                                                       \
        const float4* tb = TB;                                                 \
        float4 m0 = tb[(prow  )*S_R4 + pc4], m1 = tb[(prow  )*S_R4 + pc4+1],   \
               m2 = tb[(prow  )*S_R4 + pc4+2];                                 \
        float4 z0 = tb[(prow+2)*S_R4 + pc4], z1 = tb[(prow+2)*S_R4 + pc4+1],   \
               z2 = tb[(prow+2)*S_R4 + pc4+2];                                 \
        float4 p0 = tb[(prow+4)*S_R4 + pc4], p1 = tb[(prow+4)*S_R4 + pc4+1],   \
               p2 = tb[(prow+4)*S_R4 + pc4+2];                                 \
        float vm[12] = {m0.x,m0.y,m0.z,m0.w, m1.x,m1.y,m1.z,m1.w,              \
                        m2.x,m2.y,m2.z,m2.w};                                  \
        float vz[12] = {z0.x,z0.y,z0.z,z0.w, z1.x,z1.y,z1.z,z1.w,              \
                        z2.x,z2.y,z2.z,z2.w};                                  \
        float vp[12] = {p0.x,p0.y,p0.z,p0.w, p1.x,p1.y,p1.z,p1.w,              \
                        p2.x,p2.y,p2.z,p2.w};                                  \
        _Pragma("unroll")                                                      \
        for (int j = 0; j < 4; ++j) {                                          \
            float xc = vz[4+j];                                                \
            dot[j][0] += xc*vm[2+j];                                           \
            dot[j][1] += xc*vm[4+j];                                           \
            dot[j][2] += xc*vm[6+j];                                           \
            dot[j][3] += xc*vz[2+j];                                           \
            dot[j][4] += xc*vz[6+j];                                           \
            dot[j][5] += xc*vp[2+j];                                           \
            dot[j][6] += xc*vp[4+j];                                           \
            dot[j][7] += xc*vp[6+j];                                           \
        }                                                                      \
    }

__global__ __launch_bounds__(256) void k_sim2(const float* __restrict__ x,
                                              const float* __restrict__ wgt,
                                              const float* __restrict__ bias,
                                              float* __restrict__ ws) {
    if (ws[WS_FLAG] != 0.0f) return;   // certified: sim is dead code (flag from k_apply)

    __shared__ float mean_s[Gn], rstd_s[Gn];
    __shared__ float sc[Cn], sh[Cn];
    __shared__ float4 tile[2][NSTG];
    __shared__ float4 n2s[NSTG];

    // XCD-chunked swizzle: 448 blocks, 56 consecutive (h-adjacent) per XCD
    int lin = blockIdx.x;
    int nid = (lin & 7) * 56 + (lin >> 3);
    int b   = nid / 112;
    int rem = nid - b*112;
    int th_ = rem / 7;
    int tw_ = rem - th_*7;
    const int h0 = th_*16, w0 = tw_*64;

    combine_stats_b(ws, b, mean_s, rstd_s);
    if (threadIdx.x < Cn) {
        int c = threadIdx.x;
        float s = rstd_s[c >> 3] * wgt[c];
        sc[c] = s;
        sh[c] = bias[c] - mean_s[c >> 3] * s;
    }
    __syncthreads();

    const int tid = threadIdx.x;
    const int r0c = tid / S_R4, c40 = tid - r0c*S_R4;
    const int i1  = tid + 256;
    const bool has1 = (i1 < NSTG);
    const int r1c = i1 / S_R4, c41 = i1 - r1c*S_R4;

    const int gr0 = h0 - 2 + r0c, gc0 = (w0 >> 2) - 1 + c40;
    const bool val0 = (gr0 >= 0) & (gr0 < Hn) & (gc0 >= 0) & (gc0 < (Wn/4));
    const int gr1 = h0 - 2 + r1c, gc1 = (w0 >> 2) - 1 + c41;
    const bool val1 = has1 & (gr1 >= 0) & (gr1 < Hn) & (gc1 >= 0) & (gc1 < (Wn/4));

    const float4* xb = reinterpret_cast<const float4*>(x + (size_t)b*CHWn);
    const size_t HW4 = HWn/4;
    const size_t off0 = val0 ? ((size_t)gr0*(Wn/4) + gc0) : 0;
    const size_t off1 = val1 ? ((size_t)gr1*(Wn/4) + gc1) : 0;

    const int prow = tid >> 4;          // 0..15
    const int pc4  = tid & 15;          // 0..15

    float dot[4][8];
    #pragma unroll
    for (int j = 0; j < 4; ++j)
        #pragma unroll
        for (int k = 0; k < 8; ++k) dot[j][k] = 0.f;

    float4 a0 = {0,0,0,0}, a1 = {0,0,0,0};

    // depth-2 prefetch: channels 0 and 1 in flight before the loop
    float4 pa0 = xb[off0],        pb0 = xb[off1];
    float4 pa1 = xb[HW4 + off0],  pb1 = xb[HW4 + off1];

    for (int cc = 0; cc < Cn; cc += 2) {
        STAGE_STEP(cc,     pa0, pb0, tile[0]);
        STAGE_STEP(cc + 1, pa1, pb1, tile[1]);
    }

    n2s[r0c*S_R4 + c40] = a0;
    if (has1) n2s[r1c*S_R4 + c41] = a1;
    __syncthreads();

    {
        const float4* nb = n2s;
        float4 m0 = nb[(prow  )*S_R4 + pc4], m1 = nb[(prow  )*S_R4 + pc4+1], m2 = nb[(prow  )*S_R4 + pc4+2];
        float4 z0 = nb[(prow+2)*S_R4 + pc4], z1 = nb[(prow+2)*S_R4 + pc4+1], z2 = nb[(prow+2)*S_R4 + pc4+2];
        float4 p0 = nb[(prow+4)*S_R4 + pc4], p1 = nb[(prow+4)*S_R4 + pc4+1], p2 = nb[(prow+4)*S_R4 + pc4+2];
        float nm[12] = {m0.x,m0.y,m0.z,m0.w, m1.x,m1.y,m1.z,m1.w, m2.x,m2.y,m2.z,m2.w};
        float nz[12] = {z0.x,z0.y,z0.z,z0.w, z1.x,z1.y,z1.z,z1.w, z2.x,z2.y,z2.z,z2.w};
        float np_[12]= {p0.x,p0.y,p0.z,p0.w, p1.x,p1.y,p1.z,p1.w, p2.x,p2.y,p2.z,p2.w};
        float rm[8], rz[8], rp[8];
        #pragma unroll
        for (int e = 0; e < 8; ++e) {
            rm[e] = 1.0f / fmaxf(sqrtf(nm[2+e]), 1e-8f);
            rz[e] = 1.0f / fmaxf(sqrtf(nz[2+e]), 1e-8f);
            rp[e] = 1.0f / fmaxf(sqrtf(np_[2+e]), 1e-8f);
        }
        float* simb = ws + WS_SIM + (size_t)b*8*HWn + (size_t)(h0+prow)*Wn + (w0 + pc4*4);
        #pragma unroll
        for (int k = 0; k < 8; ++k) {
            f32x4 o;
            #pragma unroll
            for (int j = 0; j < 4; ++j) {
                float rnc = rz[2+j];
                float rnn;
                switch (k) {
                    case 0: rnn = rm[j];   break;
                    case 1: rnn = rm[2+j]; break;
                    case 2: rnn = rm[4+j]; break;
                    case 3: rnn = rz[j];   break;
                    case 4: rnn = rz[4+j]; break;
                    case 5: rnn = rp[j];   break;
                    case 6: rnn = rp[2+j]; break;
                    default: rnn = rp[4+j]; break;
                }
                o[j] = dot[j][k]*rnc*rnn;
            }
            *reinterpret_cast<f32x4*>(simb + (size_t)k*HWn) = o;
        }
    }
}

// ---------------- fallback: 3x3 convs + sigmoid gate + nearest-sample + out ----------------
__global__ __launch_bounds__(256) void k_csamp(const float* __restrict__ x,
                                               const float* __restrict__ wgt,
                                               const float* __restrict__ bias,
                                               const float* __restrict__ ow,
                                               const float* __restrict__ obias,
                                               const float* __restrict__ sw,
                                               const float* __restrict__ sbias,
                                               const float* __restrict__ ws,
                                               float* __restrict__ out) {
    if (ws[WS_FLAG] != 0.0f) return;   // certified: k_apply wrote the output

    __shared__ float mean_s[Gn], rstd_s[Gn];
    __shared__ float sc[Cn], sh[Cn];
    __shared__ float wo[144], wg[144];

    const int u  = blockIdx.x*256 + threadIdx.x;   // f4 index in [0, B*HW/4)
    const int b  = u / (HWn/4);
    const int r4 = u - b*(HWn/4);
    const int h  = r4 / (Wn/4);
    const int j  = r4 - h*(Wn/4);                  // f4 col 0..111

    combine_stats_b(ws, b, mean_s, rstd_s);        // b uniform per block
    if (threadIdx.x < Cn) {
        int c = threadIdx.x;
        float s = rstd_s[c >> 3] * wgt[c];
        sc[c] = s;
        sh[c] = bias[c] - mean_s[c >> 3] * s;
    }
    for (int i = threadIdx.x; i < 144; i += 256) { wo[i] = ow[i]; wg[i] = sw[i]; }
    __syncthreads();

    float ao0[4], ao1[4], as0[4], as1[4];
    {
        const float b0 = obias[0], b1 = obias[1], c0 = sbias[0], c1 = sbias[1];
        #pragma unroll
        for (int p = 0; p < 4; ++p) { ao0[p] = b0; ao1[p] = b1; as0[p] = c0; as1[p] = c1; }
    }

    const float* simb = ws + WS_SIM + (size_t)b*8*HWn;
    #pragma unroll 2
    for (int kc = 0; kc < 8; ++kc) {
        const float* sp = simb + (size_t)kc*HWn;
        #pragma unroll
        for (int dy = -1; dy <= 1; ++dy) {
            const int hh = h + dy;
            const bool rowok = (hh >= 0) & (hh < Hn);
            const float* rowp = sp + (size_t)hh*Wn;
            float4 Bv = {0,0,0,0};
            float Aw = 0.f, Cx = 0.f;
            if (rowok) {
                Bv = reinterpret_cast<const float4*>(rowp)[j];
                if (j > 0)   Aw = rowp[4*j - 1];
                if (j < 111) Cx = rowp[4*j + 4];
            }
            float win[6] = {Aw, Bv.x, Bv.y, Bv.z, Bv.w, Cx};
            const int wi = kc*9 + (dy+1)*3;
            const float w00 = wo[wi], w01 = wo[wi+1], w02 = wo[wi+2];
            const float w10 = wo[wi+72], w11 = wo[wi+73], w12 = wo[wi+74];
            const float g00 = wg[wi], g01 = wg[wi+1], g02 = wg[wi+2];
            const float g10 = wg[wi+72], g11 = wg[wi+73], g12 = wg[wi+74];
            #pragma unroll
            for (int p = 0; p < 4; ++p) {
                const float t0 = win[p], t1 = win[p+1], t2 = win[p+2];
                ao0[p] += w00*t0 + w01*t1 + w02*t2;
                ao1[p] += w10*t0 + w11*t1 + w12*t2;
                as0[p] += g00*t0 + g01*t1 + g02*t2;
                as1[p] += g10*t0 + g11*t1 + g12*t2;
            }
        }
    }

    // offsets -> nearest indices (exact reference arithmetic, f32)
    int ixs[4], iys[4];
    #pragma unroll
    for (int p = 0; p < 4; ++p) {
        const float o0 = ao0[p] * (1.0f / (1.0f + expf(-as0[p])));
        const float o1 = ao1[p] * (1.0f / (1.0f + expf(-as1[p])));
        const int w = 4*j + p;
        float gx  = ((float)w + 0.5f) + o0;
        float gy  = ((float)h + 0.5f) + o1;
        float ngx = 2.0f*gx/(float)Wn - 1.0f;
        float ngy = 2.0f*gy/(float)Hn - 1.0f;
        float fx  = ((ngx + 1.0f)*(float)Wn - 1.0f)*0.5f;
        float fy  = ((ngy + 1.0f)*(float)Hn - 1.0f)*0.5f;
        ixs[p] = (int)fminf(fmaxf(rintf(fx), 0.f), (float)(Wn-1));
        iys[p] = (int)fminf(fmaxf(rintf(fy), 0.f), (float)(Hn-1));
    }

    const float* xb = x + (size_t)b*CHWn;
    float* po = out + (size_t)b*CHWn + (size_t)h*Wn + 4*j;

    // Fast path: all 4 gather indices equal this thread's own float4 cell
    const bool fast = (iys[0]==h) & (ixs[0]==4*j  ) &
                      (iys[1]==h) & (ixs[1]==4*j+1) &
                      (iys[2]==h) & (ixs[2]==4*j+2) &
                      (iys[3]==h) & (ixs[3]==4*j+3);
    if (fast) {
        const size_t o = (size_t)h*Wn + 4*j;
        #pragma unroll 8
        for (int c = 0; c < Cn; ++c) {
            const f32x4 v = *reinterpret_cast<const f32x4*>(xb + (size_t)c*HWn + o);
            const float s = sc[c], t = sh[c];
            f32x4 ov;
            ov[0] = v[0]*s + t; ov[1] = v[1]*s + t;
            ov[2] = v[2]*s + t; ov[3] = v[3]*s + t;
            __builtin_nontemporal_store(ov, reinterpret_cast<f32x4*>(po + (size_t)c*HWn));
        }
    } else {
        const int base0 = iys[0]*Wn + ixs[0];
        const int base1 = iys[1]*Wn + ixs[1];
        const int base2 = iys[2]*Wn + ixs[2];
        const int base3 = iys[3]*Wn + ixs[3];
        #pragma unroll 4
        for (int c = 0; c < Cn; ++c) {
            const float* pc = xb + (size_t)c*HWn;
            const float s = sc[c], t = sh[c];
            f32x4 o;
            o[0] = pc[base0]*s + t;
            o[1] = pc[base1]*s + t;
            o[2] = pc[base2]*s + t;
            o[3] = pc[base3]*s + t;
            __builtin_nontemporal_store(o, reinterpret_cast<f32x4*>(po + (size_t)c*HWn));
        }
    }
}

extern "C" void kernel_launch(void* const* d_in, const int* in_sizes, int n_in,
                              void* d_out, int out_size, void* d_ws, size_t ws_size,
                              hipStream_t stream) {
    const float* x     = (const float*)d_in[0];  // aligned_feat
    const float* wgt   = (const float*)d_in[3];  // gn_weight
    const float* bias  = (const float*)d_in[4];  // gn_bias
    const float* ow    = (const float*)d_in[5];  // offset_w (2,8,3,3)
    const float* ob    = (const float*)d_in[6];  // offset_b (2,)
    const float* sw    = (const float*)d_in[7];  // scale_w
    const float* sb    = (const float*)d_in[8];  // scale_b
    float* out = (float*)d_out;
    float* ws  = (float*)d_ws;

    k_stats1<<<dim3(NGn, NBLKn), 256, 0, stream>>>(x, ws);
    k_apply <<<2048, 256, 0, stream>>>(x, wgt, bias, ow, ob, ws, out);
    k_sim2  <<<448, 256, 0, stream>>>(x, wgt, bias, ws);
    k_csamp <<<448, 256, 0, stream>>>(x, wgt, bias, ow, ob, sw, sb, ws, out);
}